// Round 12
// baseline (63.017 us; speedup 1.0000x reference)
//
#include <hip/hip_runtime.h>
#include <stdint.h>

// IDs in [0, 100000): 100000 bits -> 3125 u32 words; pad to 3136 (x64) so
// every bitset slice is 16B-aligned for uint4 ops.
#define NWORDS 3125
#define NWP    3136
#define NVEC   (NWP / 4)              // 784 uint4 per bitset
#define SCAN_BLOCKS 1024
#define SCAN_THREADS 512
#define NPART  8                      // partial tail bitsets (collision spread)
#define BLD_BLOCKS 16
#define BLD_THREADS 512
#define WPB  (NWP / BLD_BLOCKS)       // 196 bitset words owned per build block

// vector types with alignment relaxed to 4B (12B-stride loads)
typedef int4 __attribute__((aligned(4))) int4_a4;
typedef int2 __attribute__((aligned(4))) int2_a4;

// Fused zero+build: each block owns an id-range slice of the head/rel bitsets
// (built in LDS from ALL of neg, then plain-stored — no global pre-zero, no
// global atomics). Also grid-strides the parts array to zero (parts first
// touched by the later scan dispatch -> stream order makes this safe).
__global__ __launch_bounds__(BLD_THREADS) void buildz_kernel(
        const int* __restrict__ neg, int B,
        uint32_t* __restrict__ headb, uint32_t* __restrict__ relb,
        uint32_t* __restrict__ parts) {
    __shared__ uint32_t lh[WPB];
    __shared__ uint32_t lr[WPB];
    const int tid  = threadIdx.x;
    const int gtid = blockIdx.x * BLD_THREADS + tid;

    // zero the NPART partial tail bitsets (~25K words over 8K threads)
    for (int i = gtid; i < NPART * NWP; i += BLD_BLOCKS * BLD_THREADS)
        parts[i] = 0u;

    for (int i = tid; i < WPB; i += BLD_THREADS) { lh[i] = 0u; lr[i] = 0u; }
    __syncthreads();

    const uint32_t wlo = blockIdx.x * WPB;  // first bitset word this block owns
    const char* __restrict__ base = (const char*)neg;

#define BPROC(V) do {                                                   \
        uint32_t wh = (uint32_t)((V).x >> 5) - wlo;                     \
        uint32_t wr = (uint32_t)((V).y >> 5) - wlo;                     \
        if (wh < WPB) atomicOr(&lh[wh], 1u << ((V).x & 31));            \
        if (wr < WPB) atomicOr(&lr[wr], 1u << ((V).y & 31));            \
    } while (0)

    // 4-deep load pipeline over ALL negs (h,r via 8B loads at 12B stride;
    // 8B at offset (B-1)*12 stays in bounds)
    uint32_t i = tid;
    for (; i + 3 * BLD_THREADS < (uint32_t)B; i += 4 * BLD_THREADS) {
        int2 v0 = *(const int2_a4*)(base + i * 12u);
        int2 v1 = *(const int2_a4*)(base + (i + BLD_THREADS) * 12u);
        int2 v2 = *(const int2_a4*)(base + (i + 2 * BLD_THREADS) * 12u);
        int2 v3 = *(const int2_a4*)(base + (i + 3 * BLD_THREADS) * 12u);
        BPROC(v0); BPROC(v1); BPROC(v2); BPROC(v3);
    }
    for (; i < (uint32_t)B; i += BLD_THREADS) {
        int2 v = *(const int2_a4*)(base + i * 12u);
        BPROC(v);
    }
#undef BPROC

    __syncthreads();
    // plain-store this block's slices (no other block writes these words)
    for (int w = tid; w < WPB; w += BLD_THREADS) {
        headb[wlo + w] = lh[w];
        relb[wlo + w] = lr[w];
    }
}

// Stream mapped_triples (overlapping 16B loads at 12B stride; h,r,t arrive in
// .x,.y,.z — no repack). Branchless h&r test. Surviving tails marked in a
// per-block LDS bitset, flushed via global atomicOr into one of NPART partial
// bitsets (blockIdx&7), L2-resident.  [identical to R7]
__global__ __launch_bounds__(SCAN_THREADS, 8) void scan_triples_kernel(
        const int* __restrict__ mt, int N,
        const uint32_t* __restrict__ headb,
        const uint32_t* __restrict__ relb,
        uint32_t* __restrict__ parts) {
    __shared__ __align__(16) uint32_t sh[NWP];
    __shared__ __align__(16) uint32_t sr[NWP];
    __shared__ __align__(16) uint32_t st[NWP];

    uint4* sh4 = (uint4*)sh;
    uint4* sr4 = (uint4*)sr;
    uint4* st4 = (uint4*)st;
    const uint4* hb4 = (const uint4*)headb;
    const uint4* rb4 = (const uint4*)relb;
    for (int i = threadIdx.x; i < NVEC; i += blockDim.x) {
        sh4[i] = hb4[i];
        sr4[i] = rb4[i];
        st4[i] = make_uint4(0u, 0u, 0u, 0u);
    }
    __syncthreads();

    const uint32_t tid = blockIdx.x * blockDim.x + threadIdx.x;
    const uint32_t stride = gridDim.x * blockDim.x;
    const char* __restrict__ base = (const char*)mt;

    // all but last triple: in-bounds 4B over-read because triple i+1 exists
    for (uint32_t i = tid; i < (uint32_t)(N - 1); i += stride) {
        int4 v = *(const int4_a4*)(base + i * 12u);
        int h = v.x, r = v.y, t = v.z;
        uint32_t hbit = (sh[h >> 5] >> (h & 31)) & 1u;
        uint32_t rbit = (sr[r >> 5] >> (r & 31)) & 1u;
        if (hbit & rbit) {
            uint32_t bit = 1u << (t & 31);
            if (!(st[t >> 5] & bit)) atomicOr(&st[t >> 5], bit);
        }
    }
    if (tid == 0) {  // last triple, scalar (no over-read)
        int h = mt[(size_t)(N - 1) * 3 + 0];
        int r = mt[(size_t)(N - 1) * 3 + 1];
        int t = mt[(size_t)(N - 1) * 3 + 2];
        if (((sh[h >> 5] >> (h & 31)) & 1u) && ((sr[r >> 5] >> (r & 31)) & 1u))
            atomicOr(&st[t >> 5], 1u << (t & 31));
    }

    __syncthreads();
    // flush nonzero words straight into one of NPART global partial bitsets
    uint32_t* dst = parts + (size_t)(blockIdx.x & (NPART - 1)) * NWP;
    for (int i = threadIdx.x; i < NWORDS; i += blockDim.x) {
        uint32_t v = st[i];
        if (v) atomicOr(&dst[i], v);
    }
}

__global__ void finalize_kernel(const int* __restrict__ neg, int B,
                                const uint32_t* __restrict__ parts,
                                int* __restrict__ out) {
    int b = blockIdx.x * blockDim.x + threadIdx.x;
    if (b >= B) return;
    int h = neg[b * 3 + 0];
    int r = neg[b * 3 + 1];
    int t = neg[b * 3 + 2];
    int w = t >> 5;
    uint32_t acc = 0u;
#pragma unroll
    for (int c = 0; c < NPART; ++c) acc |= parts[c * NWP + w];
    bool filtered = (acc >> (t & 31)) & 1u;
    int keep = filtered ? 0 : 1;
    out[b * 3 + 0] = keep ? h : -1;
    out[b * 3 + 1] = keep ? r : -1;
    out[b * 3 + 2] = keep ? t : -1;
    out[3 * B + b] = keep;  // keep_mask as 0/1 int32
}

extern "C" void kernel_launch(void* const* d_in, const int* in_sizes, int n_in,
                              void* d_out, int out_size, void* d_ws, size_t ws_size,
                              hipStream_t stream) {
    const int* neg = (const int*)d_in[0];   // [B,3] int32
    const int* mt  = (const int*)d_in[1];   // [N,3] int32
    int B = in_sizes[0] / 3;
    int N = in_sizes[1] / 3;
    int* out = (int*)d_out;

    uint32_t* ws    = (uint32_t*)d_ws;
    uint32_t* headb = ws;               // NWP
    uint32_t* relb  = ws + NWP;         // NWP
    uint32_t* parts = ws + 2 * NWP;     // NPART * NWP (~100 KB, L2-resident)

    // 3 dispatches: fused zero+build -> scan -> finalize
    buildz_kernel<<<BLD_BLOCKS, BLD_THREADS, 0, stream>>>(neg, B, headb, relb,
                                                          parts);
    scan_triples_kernel<<<SCAN_BLOCKS, SCAN_THREADS, 0, stream>>>(
        mt, N, headb, relb, parts);
    finalize_kernel<<<(B + 255) / 256, 256, 0, stream>>>(neg, B, parts, out);
}

// Round 13
// 56.624 us; speedup vs baseline: 1.1129x; 1.1129x over previous
//
#include <hip/hip_runtime.h>
#include <stdint.h>

// IDs in [0, 100000): 100000 bits -> 3125 u32 words; pad to 3136 (x64) so
// every bitset slice is 16B-aligned for uint4 ops.
#define NWORDS 3125
#define NWP    3136
#define NVEC   (NWP / 4)              // 784 uint4 per bitset
#define SCAN_BLOCKS 1024
#define SCAN_THREADS 512
#define NPART  8                      // partial tail bitsets (collision spread)

// vector types with alignment relaxed to 4B (12B-stride loads)
typedef int4 __attribute__((aligned(4))) int4_a4;
typedef int2 __attribute__((aligned(4))) int2_a4;

__global__ void zero_kernel(uint32_t* __restrict__ w, int n) {
    int i = blockIdx.x * blockDim.x + threadIdx.x;
    if (i < n) w[i] = 0u;
}

__global__ void build_hr_kernel(const int* __restrict__ neg, int B,
                                uint32_t* __restrict__ headb,
                                uint32_t* __restrict__ relb) {
    int b = blockIdx.x * blockDim.x + threadIdx.x;
    if (b < B - 1) {
        // one 8B vector load at 12B stride (h,r in .x,.y); in-bounds because
        // triple b+1 exists
        int2 v = *(const int2_a4*)((const char*)neg + (uint32_t)b * 12u);
        atomicOr(&headb[v.x >> 5], 1u << (v.x & 31));
        atomicOr(&relb[v.y >> 5], 1u << (v.y & 31));
    } else if (b == B - 1) {  // last triple scalar: no over-read
        int h = neg[b * 3 + 0];
        int r = neg[b * 3 + 1];
        atomicOr(&headb[h >> 5], 1u << (h & 31));
        atomicOr(&relb[r >> 5], 1u << (r & 31));
    }
}

// Stream mapped_triples (overlapping 16B loads at 12B stride; h,r,t arrive in
// .x,.y,.z — no repack). Branchless h&r test. Surviving tails marked in a
// per-block LDS bitset, flushed via global atomicOr into one of NPART partial
// bitsets (blockIdx&7), L2-resident.  [identical to R7]
__global__ __launch_bounds__(SCAN_THREADS, 8) void scan_triples_kernel(
        const int* __restrict__ mt, int N,
        const uint32_t* __restrict__ headb,
        const uint32_t* __restrict__ relb,
        uint32_t* __restrict__ parts) {
    __shared__ __align__(16) uint32_t sh[NWP];
    __shared__ __align__(16) uint32_t sr[NWP];
    __shared__ __align__(16) uint32_t st[NWP];

    uint4* sh4 = (uint4*)sh;
    uint4* sr4 = (uint4*)sr;
    uint4* st4 = (uint4*)st;
    const uint4* hb4 = (const uint4*)headb;
    const uint4* rb4 = (const uint4*)relb;
    for (int i = threadIdx.x; i < NVEC; i += blockDim.x) {
        sh4[i] = hb4[i];
        sr4[i] = rb4[i];
        st4[i] = make_uint4(0u, 0u, 0u, 0u);
    }
    __syncthreads();

    const uint32_t tid = blockIdx.x * blockDim.x + threadIdx.x;
    const uint32_t stride = gridDim.x * blockDim.x;
    const char* __restrict__ base = (const char*)mt;

    // all but last triple: in-bounds 4B over-read because triple i+1 exists
    for (uint32_t i = tid; i < (uint32_t)(N - 1); i += stride) {
        int4 v = *(const int4_a4*)(base + i * 12u);
        int h = v.x, r = v.y, t = v.z;
        uint32_t hbit = (sh[h >> 5] >> (h & 31)) & 1u;
        uint32_t rbit = (sr[r >> 5] >> (r & 31)) & 1u;
        if (hbit & rbit) {
            uint32_t bit = 1u << (t & 31);
            if (!(st[t >> 5] & bit)) atomicOr(&st[t >> 5], bit);
        }
    }
    if (tid == 0) {  // last triple, scalar (no over-read)
        int h = mt[(size_t)(N - 1) * 3 + 0];
        int r = mt[(size_t)(N - 1) * 3 + 1];
        int t = mt[(size_t)(N - 1) * 3 + 2];
        if (((sh[h >> 5] >> (h & 31)) & 1u) && ((sr[r >> 5] >> (r & 31)) & 1u))
            atomicOr(&st[t >> 5], 1u << (t & 31));
    }

    __syncthreads();
    // flush nonzero words straight into one of NPART global partial bitsets
    uint32_t* dst = parts + (size_t)(blockIdx.x & (NPART - 1)) * NWP;
    for (int i = threadIdx.x; i < NWORDS; i += blockDim.x) {
        uint32_t v = st[i];
        if (v) atomicOr(&dst[i], v);
    }
}

__global__ void finalize_kernel(const int* __restrict__ neg, int B,
                                const uint32_t* __restrict__ parts,
                                int* __restrict__ out) {
    int b = blockIdx.x * blockDim.x + threadIdx.x;
    if (b >= B) return;
    int h, r, t;
    if (b < B - 1) {
        // one 16B vector load at 12B stride (h,r,t in .x,.y,.z); in-bounds
        // because triple b+1 exists
        int4 v = *(const int4_a4*)((const char*)neg + (uint32_t)b * 12u);
        h = v.x; r = v.y; t = v.z;
    } else {  // last triple scalar: no over-read
        h = neg[b * 3 + 0];
        r = neg[b * 3 + 1];
        t = neg[b * 3 + 2];
    }
    int w = t >> 5;
    uint32_t acc = 0u;
#pragma unroll
    for (int c = 0; c < NPART; ++c) acc |= parts[c * NWP + w];
    bool filtered = (acc >> (t & 31)) & 1u;
    int keep = filtered ? 0 : 1;
    out[b * 3 + 0] = keep ? h : -1;
    out[b * 3 + 1] = keep ? r : -1;
    out[b * 3 + 2] = keep ? t : -1;
    out[3 * B + b] = keep;  // keep_mask as 0/1 int32
}

extern "C" void kernel_launch(void* const* d_in, const int* in_sizes, int n_in,
                              void* d_out, int out_size, void* d_ws, size_t ws_size,
                              hipStream_t stream) {
    const int* neg = (const int*)d_in[0];   // [B,3] int32
    const int* mt  = (const int*)d_in[1];   // [N,3] int32
    int B = in_sizes[0] / 3;
    int N = in_sizes[1] / 3;
    int* out = (int*)d_out;

    uint32_t* ws    = (uint32_t*)d_ws;
    uint32_t* headb = ws;               // NWP
    uint32_t* relb  = ws + NWP;         // NWP
    uint32_t* parts = ws + 2 * NWP;     // NPART * NWP (~100 KB, L2-resident)

    // zero head/rel bitsets + partial tail bitsets (ws not re-poisoned
    // between replays — must re-zero every call)
    zero_kernel<<<((2 + NPART) * NWP + 255) / 256, 256, 0, stream>>>(
        ws, (2 + NPART) * NWP);
    build_hr_kernel<<<(B + 255) / 256, 256, 0, stream>>>(neg, B, headb, relb);
    scan_triples_kernel<<<SCAN_BLOCKS, SCAN_THREADS, 0, stream>>>(
        mt, N, headb, relb, parts);
    finalize_kernel<<<(B + 255) / 256, 256, 0, stream>>>(neg, B, parts, out);
}

// Round 14
// 56.017 us; speedup vs baseline: 1.1250x; 1.0108x over previous
//
#include <hip/hip_runtime.h>
#include <stdint.h>

// ===== FINAL: lock-in revert to R7 (best measured: 55.8 us) =====
// Structure: zero -> build_hr -> scan -> finalize (4 dispatches).
// Scan ~37.8us (ablation-measured), ~81% of its 192MB stream floor;
// remaining ~18us is small-kernel dispatch + graph-replay fixed overhead,
// shown structural by R5/R10/R11/R12/R13 failures.

// IDs in [0, 100000): 100000 bits -> 3125 u32 words; pad to 3136 (x64) so
// every bitset slice is 16B-aligned for uint4 ops.
#define NWORDS 3125
#define NWP    3136
#define NVEC   (NWP / 4)              // 784 uint4 per bitset
#define SCAN_BLOCKS 1024
#define SCAN_THREADS 512
#define NPART  8                      // partial tail bitsets (collision spread)

// int4 with alignment relaxed to 4B: gfx950 supports dword-aligned dwordx4.
typedef int4 __attribute__((aligned(4))) int4_a4;

__global__ void zero_kernel(uint32_t* __restrict__ w, int n) {
    int i = blockIdx.x * blockDim.x + threadIdx.x;
    if (i < n) w[i] = 0u;
}

__global__ void build_hr_kernel(const int* __restrict__ neg, int B,
                                uint32_t* __restrict__ headb,
                                uint32_t* __restrict__ relb) {
    int b = blockIdx.x * blockDim.x + threadIdx.x;
    if (b >= B) return;
    int h = neg[b * 3 + 0];
    int r = neg[b * 3 + 1];
    atomicOr(&headb[h >> 5], 1u << (h & 31));
    atomicOr(&relb[r >> 5], 1u << (r & 31));
}

// Stream mapped_triples (overlapping 16B loads at 12B stride; h,r,t arrive in
// .x,.y,.z — no repack). Branchless h&r test. Surviving tails marked in a
// per-block LDS bitset, flushed via global atomicOr into one of NPART partial
// bitsets (blockIdx&7), L2-resident.
__global__ __launch_bounds__(SCAN_THREADS, 8) void scan_triples_kernel(
        const int* __restrict__ mt, int N,
        const uint32_t* __restrict__ headb,
        const uint32_t* __restrict__ relb,
        uint32_t* __restrict__ parts) {
    __shared__ __align__(16) uint32_t sh[NWP];
    __shared__ __align__(16) uint32_t sr[NWP];
    __shared__ __align__(16) uint32_t st[NWP];

    uint4* sh4 = (uint4*)sh;
    uint4* sr4 = (uint4*)sr;
    uint4* st4 = (uint4*)st;
    const uint4* hb4 = (const uint4*)headb;
    const uint4* rb4 = (const uint4*)relb;
    for (int i = threadIdx.x; i < NVEC; i += blockDim.x) {
        sh4[i] = hb4[i];
        sr4[i] = rb4[i];
        st4[i] = make_uint4(0u, 0u, 0u, 0u);
    }
    __syncthreads();

    const uint32_t tid = blockIdx.x * blockDim.x + threadIdx.x;
    const uint32_t stride = gridDim.x * blockDim.x;
    const char* __restrict__ base = (const char*)mt;

    // all but last triple: in-bounds 4B over-read because triple i+1 exists
    for (uint32_t i = tid; i < (uint32_t)(N - 1); i += stride) {
        int4 v = *(const int4_a4*)(base + i * 12u);
        int h = v.x, r = v.y, t = v.z;
        uint32_t hbit = (sh[h >> 5] >> (h & 31)) & 1u;
        uint32_t rbit = (sr[r >> 5] >> (r & 31)) & 1u;
        if (hbit & rbit) {
            uint32_t bit = 1u << (t & 31);
            if (!(st[t >> 5] & bit)) atomicOr(&st[t >> 5], bit);
        }
    }
    if (tid == 0) {  // last triple, scalar (no over-read)
        int h = mt[(size_t)(N - 1) * 3 + 0];
        int r = mt[(size_t)(N - 1) * 3 + 1];
        int t = mt[(size_t)(N - 1) * 3 + 2];
        if (((sh[h >> 5] >> (h & 31)) & 1u) && ((sr[r >> 5] >> (r & 31)) & 1u))
            atomicOr(&st[t >> 5], 1u << (t & 31));
    }

    __syncthreads();
    // flush nonzero words straight into one of NPART global partial bitsets
    uint32_t* dst = parts + (size_t)(blockIdx.x & (NPART - 1)) * NWP;
    for (int i = threadIdx.x; i < NWORDS; i += blockDim.x) {
        uint32_t v = st[i];
        if (v) atomicOr(&dst[i], v);
    }
}

__global__ void finalize_kernel(const int* __restrict__ neg, int B,
                                const uint32_t* __restrict__ parts,
                                int* __restrict__ out) {
    int b = blockIdx.x * blockDim.x + threadIdx.x;
    if (b >= B) return;
    int h = neg[b * 3 + 0];
    int r = neg[b * 3 + 1];
    int t = neg[b * 3 + 2];
    int w = t >> 5;
    uint32_t acc = 0u;
#pragma unroll
    for (int c = 0; c < NPART; ++c) acc |= parts[c * NWP + w];
    bool filtered = (acc >> (t & 31)) & 1u;
    int keep = filtered ? 0 : 1;
    out[b * 3 + 0] = keep ? h : -1;
    out[b * 3 + 1] = keep ? r : -1;
    out[b * 3 + 2] = keep ? t : -1;
    out[3 * B + b] = keep;  // keep_mask as 0/1 int32
}

extern "C" void kernel_launch(void* const* d_in, const int* in_sizes, int n_in,
                              void* d_out, int out_size, void* d_ws, size_t ws_size,
                              hipStream_t stream) {
    const int* neg = (const int*)d_in[0];   // [B,3] int32
    const int* mt  = (const int*)d_in[1];   // [N,3] int32
    int B = in_sizes[0] / 3;
    int N = in_sizes[1] / 3;
    int* out = (int*)d_out;

    uint32_t* ws    = (uint32_t*)d_ws;
    uint32_t* headb = ws;               // NWP
    uint32_t* relb  = ws + NWP;         // NWP
    uint32_t* parts = ws + 2 * NWP;     // NPART * NWP (~100 KB, L2-resident)

    // zero head/rel bitsets + partial tail bitsets (ws not re-poisoned
    // between replays — must re-zero every call)
    zero_kernel<<<((2 + NPART) * NWP + 255) / 256, 256, 0, stream>>>(
        ws, (2 + NPART) * NWP);
    build_hr_kernel<<<(B + 255) / 256, 256, 0, stream>>>(neg, B, headb, relb);
    scan_triples_kernel<<<SCAN_BLOCKS, SCAN_THREADS, 0, stream>>>(
        mt, N, headb, relb, parts);
    finalize_kernel<<<(B + 255) / 256, 256, 0, stream>>>(neg, B, parts, out);
}